// Round 6
// baseline (416.608 us; speedup 1.0000x reference)
//
#include <hip/hip_runtime.h>
#include <math.h>
#include <stdint.h>

#define BB 2
#define NN 512
#define CC 256
#define HH 256
#define WW 256
#define DIN 12544    // C * 7 * 7
#define OUT1 1024
#define NCLS 11      // NUM_CLASSES + 1
#define NROI 1024    // B * N
#define SK1 8        // split-K for FC1 (12544 = 8 * 1568)
#define SK2 2        // split-K for FC2 (1024 = 2 * 512)

typedef short bf16x8 __attribute__((ext_vector_type(8)));
typedef float f32x4 __attribute__((ext_vector_type(4)));

__device__ inline unsigned short f2bf(float f) {
  unsigned int u = __float_as_uint(f);
  u += 0x7FFF + ((u >> 16) & 1);  // round-to-nearest-even
  return (unsigned short)(u >> 16);
}
__device__ inline float bf2f(unsigned short h) {
  return __uint_as_float(((unsigned int)h) << 16);
}
__device__ inline float4 ld_bf4(const unsigned short* p) {
  ushort4 r = *(const ushort4*)p;
  return make_float4(bf2f(r.x), bf2f(r.y), bf2f(r.z), bf2f(r.w));
}

// async global->LDS, 16B per lane; lds ptr must be wave-uniform base + lane*16
__device__ inline void gll16(const void* g, void* l) {
  __builtin_amdgcn_global_load_lds(
      reinterpret_cast<const __attribute__((address_space(1))) void*>(
          reinterpret_cast<uintptr_t>(g)),
      reinterpret_cast<__attribute__((address_space(3))) void*>(
          (unsigned int)reinterpret_cast<uintptr_t>(l)),
      16, 0, 0);
}

// ---------------------------------------------------------------------------
// NCHW fp32 -> NHWC bf16, v2. Tile 128c x 128hw. All 16 loads register-staged
// (max memory parallelism), 512B read bursts, 256B contiguous write bursts.
// LDS bf16 [hw][c], stride 132 (264B rows, 8B-aligned).
// ---------------------------------------------------------------------------
__global__ __launch_bounds__(256) void transpose_to_hwc_bf16(
    const float* __restrict__ in, unsigned short* __restrict__ out) {
  __shared__ unsigned short tile[128 * 132];
  int b = blockIdx.z;
  int hw0 = blockIdx.x * 128;
  int c0 = blockIdx.y * 128;
  int tid = threadIdx.x;
  int hl = tid & 31;  // lane within half-wave: hw chunk
  int hr = tid >> 5;  // 0..7: c row group
  const float* base = in + ((size_t)b * CC + c0) * (HH * WW) + hw0;
  float4 v[16];
#pragma unroll
  for (int p = 0; p < 16; ++p) {
    int c = p * 8 + hr;
    v[p] = *(const float4*)(base + (size_t)c * (HH * WW) + hl * 4);
  }
#pragma unroll
  for (int p = 0; p < 16; ++p) {
    int c = p * 8 + hr;
    int hw = hl * 4;
    tile[(hw + 0) * 132 + c] = f2bf(v[p].x);
    tile[(hw + 1) * 132 + c] = f2bf(v[p].y);
    tile[(hw + 2) * 132 + c] = f2bf(v[p].z);
    tile[(hw + 3) * 132 + c] = f2bf(v[p].w);
  }
  __syncthreads();
  unsigned short* ob = out + ((size_t)b * (HH * WW) + hw0) * CC + c0;
#pragma unroll
  for (int p = 0; p < 16; ++p) {
    int r = p * 8 + hr;
    ushort4 o = *(const ushort4*)&tile[r * 132 + hl * 4];
    *(ushort4*)(ob + (size_t)r * CC + hl * 4) = o;
  }
}

// ---------------------------------------------------------------------------
__device__ inline void bilin(float gy, float gx, int& y0, int& x0, int& y1,
                             int& x1, float& w00, float& w01, float& w10,
                             float& w11) {
  float valid = (gy > -1.f && gy < 256.f && gx > -1.f && gx < 256.f) ? 0.25f : 0.f;
  float y = fminf(fmaxf(gy, 0.f), 255.f);
  float x = fminf(fmaxf(gx, 0.f), 255.f);
  float yf = floorf(y), xf = floorf(x);
  y0 = (int)yf; x0 = (int)xf;
  y1 = min(y0 + 1, 255); x1 = min(x0 + 1, 255);
  float ly = y - yf, lx = x - xf, hy = 1.f - ly, hx = 1.f - lx;
  w00 = hy * hx * valid; w01 = hy * lx * valid;
  w10 = ly * hx * valid; w11 = ly * lx * valid;
}

// ---------------------------------------------------------------------------
// ROI align rotated from NHWC bf16. pooled layout NOW NATURAL: [roi][c*49+bin]
// (k order matches W1 rows, so cvt_w needs no permutation). Row staged in LDS,
// written out fully coalesced as uint4.
// ---------------------------------------------------------------------------
__global__ __launch_bounds__(256) void roi_align_hwc(
    const unsigned short* __restrict__ fhwc, const float* __restrict__ props,
    unsigned short* __restrict__ pooled) {
  __shared__ unsigned short prow[DIN];
  int roi = blockIdx.x;
  int b = roi >> 9;
  const float* p = props + (size_t)roi * 5;
  float cx = p[0], cy = p[1], w = p[2], h = p[3], th = p[4];
  float sn = sinf(th), cs = cosf(th);
  int tid = threadIdx.x;
  int wave = tid >> 6, lane = tid & 63;
  int c4 = lane * 4;
  const unsigned short* fb = fhwc + (size_t)b * HH * WW * CC;

  for (int bin = wave; bin < 49; bin += 4) {
    int py = bin / 7, px = bin - py * 7;
    float a0 = 0.f, a1 = 0.f, a2 = 0.f, a3 = 0.f;
#pragma unroll
    for (int sy = 0; sy < 2; ++sy) {
#pragma unroll
      for (int sx = 0; sx < 2; ++sx) {
        float ys = -0.5f * h + (h / 7.0f) * ((float)py + ((float)sy + 0.5f) * 0.5f);
        float xs = -0.5f * w + (w / 7.0f) * ((float)px + ((float)sx + 0.5f) * 0.5f);
        float gx = cx + xs * cs - ys * sn;
        float gy = cy + xs * sn + ys * cs;
        int y0, x0, y1, x1; float w00, w01, w10, w11;
        bilin(gy, gx, y0, x0, y1, x1, w00, w01, w10, w11);
        float4 v00 = ld_bf4(fb + ((size_t)(y0 * WW + x0)) * CC + c4);
        float4 v01 = ld_bf4(fb + ((size_t)(y0 * WW + x1)) * CC + c4);
        float4 v10 = ld_bf4(fb + ((size_t)(y1 * WW + x0)) * CC + c4);
        float4 v11 = ld_bf4(fb + ((size_t)(y1 * WW + x1)) * CC + c4);
        a0 += w00 * v00.x + w01 * v01.x + w10 * v10.x + w11 * v11.x;
        a1 += w00 * v00.y + w01 * v01.y + w10 * v10.y + w11 * v11.y;
        a2 += w00 * v00.z + w01 * v01.z + w10 * v10.z + w11 * v11.z;
        a3 += w00 * v00.w + w01 * v01.w + w10 * v10.w + w11 * v11.w;
      }
    }
    prow[(c4 + 0) * 49 + bin] = f2bf(a0);
    prow[(c4 + 1) * 49 + bin] = f2bf(a1);
    prow[(c4 + 2) * 49 + bin] = f2bf(a2);
    prow[(c4 + 3) * 49 + bin] = f2bf(a3);
  }
  __syncthreads();
  const uint4* src = (const uint4*)prow;
  uint4* dst = (uint4*)(pooled + (size_t)roi * DIN);
  for (int i = tid; i < DIN / 8; i += 256) dst[i] = src[i];
}

// Fallback: direct NCHW gather (small-ws path), natural-k layout
__global__ __launch_bounds__(256) void roi_align_nchw(
    const float* __restrict__ feat, const float* __restrict__ props,
    unsigned short* __restrict__ pooled) {
  __shared__ unsigned short prow[DIN];
  int roi = blockIdx.x;
  int b = roi >> 9;
  int c = threadIdx.x;
  const float* p = props + (size_t)roi * 5;
  float cx = p[0], cy = p[1], w = p[2], h = p[3], th = p[4];
  float sn = sinf(th), cs = cosf(th);
  const float* fb = feat + ((size_t)b * CC + c) * (HH * WW);
  for (int bin = 0; bin < 49; ++bin) {
    int py = bin / 7, px = bin - py * 7;
    float acc = 0.f;
#pragma unroll
    for (int sy = 0; sy < 2; ++sy) {
#pragma unroll
      for (int sx = 0; sx < 2; ++sx) {
        float ys = -0.5f * h + (h / 7.0f) * ((float)py + ((float)sy + 0.5f) * 0.5f);
        float xs = -0.5f * w + (w / 7.0f) * ((float)px + ((float)sx + 0.5f) * 0.5f);
        float gx = cx + xs * cs - ys * sn;
        float gy = cy + xs * sn + ys * cs;
        int y0, x0, y1, x1; float w00, w01, w10, w11;
        bilin(gy, gx, y0, x0, y1, x1, w00, w01, w10, w11);
        acc += w00 * fb[(size_t)y0 * WW + x0] + w01 * fb[(size_t)y0 * WW + x1] +
               w10 * fb[(size_t)y1 * WW + x0] + w11 * fb[(size_t)y1 * WW + x1];
      }
    }
    prow[c * 49 + bin] = f2bf(acc);
  }
  __syncthreads();
  const uint4* src = (const uint4*)prow;
  uint4* dst = (uint4*)(pooled + (size_t)roi * DIN);
  for (int i = threadIdx.x; i < DIN / 8; i += 256) dst[i] = src[i];
}

// ---------------------------------------------------------------------------
// Plain weight transpose+cvt: in [K][1024] fp32 -> out [1024][K] bf16.
// Tile 64k x 256n; 16 register-staged loads; LDS [n][k] stride 68.
// ---------------------------------------------------------------------------
__global__ __launch_bounds__(256) void cvt_w_t(const float* __restrict__ in,
                                               unsigned short* __restrict__ out,
                                               int K) {
  __shared__ unsigned short tile[256 * 68];
  int k0 = blockIdx.x * 64, n0 = blockIdx.y * 256;
  int tid = threadIdx.x;
  int l = tid & 63, w = tid >> 6;
  float4 v[16];
#pragma unroll
  for (int p = 0; p < 16; ++p) {
    int k = p * 4 + w;
    v[p] = *(const float4*)(in + (size_t)(k0 + k) * OUT1 + n0 + l * 4);
  }
#pragma unroll
  for (int p = 0; p < 16; ++p) {
    int k = p * 4 + w;
    int n = l * 4;
    tile[(n + 0) * 68 + k] = f2bf(v[p].x);
    tile[(n + 1) * 68 + k] = f2bf(v[p].y);
    tile[(n + 2) * 68 + k] = f2bf(v[p].z);
    tile[(n + 3) * 68 + k] = f2bf(v[p].w);
  }
  __syncthreads();
  int wl = tid & 15, wr = tid >> 4;
#pragma unroll
  for (int p = 0; p < 16; ++p) {
    int n = p * 16 + wr;
    ushort4 o = *(const ushort4*)&tile[n * 68 + wl * 4];
    *(ushort4*)(out + (size_t)(n0 + n) * K + k0 + wl * 4) = o;
  }
}

// ---------------------------------------------------------------------------
// Pack head weights: Wcat bf16 [16][1024]; bcat[16].
// ---------------------------------------------------------------------------
__global__ __launch_bounds__(256) void pack_head_w(
    const float* __restrict__ Wcls, const float* __restrict__ bcls,
    const float* __restrict__ Wreg, const float* __restrict__ breg,
    unsigned short* __restrict__ Wcat, float* __restrict__ bcat) {
  int o = blockIdx.x;
  int t = threadIdx.x;
#pragma unroll
  for (int j = 0; j < 4; ++j) {
    int k = t * 4 + j;
    float v = (o < NCLS) ? Wcls[(size_t)k * NCLS + o]
                         : Wreg[(size_t)k * 5 + (o - NCLS)];
    Wcat[(size_t)o * OUT1 + k] = f2bf(v);
  }
  if (t == 0) bcat[o] = (o < NCLS) ? bcls[o] : breg[o - NCLS];
}

// ---------------------------------------------------------------------------
// MFMA GEMM, 128x128 tile, BK=32, split-K partials -> bf16.
// A [M][K] bf16 row-major; Bw [N][K] bf16 row-major.
// ---------------------------------------------------------------------------
__global__ __launch_bounds__(256) void gemm_mfma_128(
    const unsigned short* __restrict__ A, const unsigned short* __restrict__ Bw,
    unsigned short* __restrict__ part, int K, int Ks) {
  __shared__ short As[128 * 32];
  __shared__ short Bs[128 * 32];
  int tid = threadIdx.x;
  int w = tid >> 6, lane = tid & 63;
  int quad = lane >> 4, l16 = lane & 15;
  int m0 = blockIdx.y * 128, n0 = blockIdx.x * 128;
  int bz = blockIdx.z;
  int wm = w >> 1, wn = w & 1;

  const char* pA = (const char*)A +
      ((size_t)(m0 + 32 * w + (lane >> 2)) * K + (size_t)bz * Ks) * 2 +
      (lane & 3) * 16;
  const char* pB = (const char*)Bw +
      ((size_t)(n0 + 32 * w + (lane >> 2)) * K + (size_t)bz * Ks) * 2 +
      (lane & 3) * 16;
  short* la = &As[w * 1024];
  short* lb = &Bs[w * 1024];
  const size_t rstep = (size_t)K * 2 * 16;  // +16 rows

  f32x4 acc[4][4] = {};
  int aoff[4], boff[4];
#pragma unroll
  for (int t = 0; t < 4; ++t) {
    aoff[t] = (wm * 64 + t * 16 + l16) * 32 + quad * 8;
    boff[t] = (wn * 64 + t * 16 + l16) * 32 + quad * 8;
  }

  for (int kk = 0; kk < Ks; kk += 32) {
    __syncthreads();  // prior reads done before LDS overwrite
    gll16(pA, la);
    gll16(pA + rstep, la + 512);
    gll16(pB, lb);
    gll16(pB + rstep, lb + 512);
    pA += 64; pB += 64;
    __syncthreads();  // vmcnt(0) drained -> LDS valid
    bf16x8 af[4], bfr[4];
#pragma unroll
    for (int t = 0; t < 4; ++t) af[t] = *(const bf16x8*)&As[aoff[t]];
#pragma unroll
    for (int t = 0; t < 4; ++t) bfr[t] = *(const bf16x8*)&Bs[boff[t]];
#pragma unroll
    for (int mt = 0; mt < 4; ++mt)
#pragma unroll
      for (int nt = 0; nt < 4; ++nt)
        acc[mt][nt] = __builtin_amdgcn_mfma_f32_16x16x32_bf16(
            af[mt], bfr[nt], acc[mt][nt], 0, 0, 0);
  }

  unsigned short* pp = part + (size_t)bz * (OUT1 * NROI);
#pragma unroll
  for (int mt = 0; mt < 4; ++mt)
#pragma unroll
    for (int nt = 0; nt < 4; ++nt) {
      int col = n0 + wn * 64 + nt * 16 + l16;
#pragma unroll
      for (int r = 0; r < 4; ++r) {
        int row = m0 + wm * 64 + mt * 16 + quad * 4 + r;
        pp[(size_t)row * OUT1 + col] = f2bf(acc[mt][nt][r]);
      }
    }
}

// split-K reduce + bias + relu -> bf16 (SK1 bf16 partials), 8 elems/thread
__global__ __launch_bounds__(256) void reduce_relu_bf16(
    const unsigned short* __restrict__ part, const float* __restrict__ bias,
    unsigned short* __restrict__ out) {
  int i = blockIdx.x * 256 + threadIdx.x;  // ushort8 index
  int base = i * 8;
  int col = base & (OUT1 - 1);
  float s[8] = {};
#pragma unroll
  for (int z = 0; z < SK1; ++z) {
    uint4 v = *(const uint4*)(part + (size_t)z * (NROI * OUT1) + base);
    s[0] += __uint_as_float(v.x << 16);
    s[1] += __uint_as_float(v.x & 0xFFFF0000u);
    s[2] += __uint_as_float(v.y << 16);
    s[3] += __uint_as_float(v.y & 0xFFFF0000u);
    s[4] += __uint_as_float(v.z << 16);
    s[5] += __uint_as_float(v.z & 0xFFFF0000u);
    s[6] += __uint_as_float(v.w << 16);
    s[7] += __uint_as_float(v.w & 0xFFFF0000u);
  }
  float4 b0 = *(const float4*)(bias + col);
  float4 b1 = *(const float4*)(bias + col + 4);
  uint4 o;
  o.x = (unsigned int)f2bf(fmaxf(s[0] + b0.x, 0.f)) |
        ((unsigned int)f2bf(fmaxf(s[1] + b0.y, 0.f)) << 16);
  o.y = (unsigned int)f2bf(fmaxf(s[2] + b0.z, 0.f)) |
        ((unsigned int)f2bf(fmaxf(s[3] + b0.w, 0.f)) << 16);
  o.z = (unsigned int)f2bf(fmaxf(s[4] + b1.x, 0.f)) |
        ((unsigned int)f2bf(fmaxf(s[5] + b1.y, 0.f)) << 16);
  o.w = (unsigned int)f2bf(fmaxf(s[6] + b1.z, 0.f)) |
        ((unsigned int)f2bf(fmaxf(s[7] + b1.w, 0.f)) << 16);
  *(uint4*)(out + base) = o;
}

// ---------------------------------------------------------------------------
// MFMA GEMM, 64x64 tile, BK=64, split-K partials fp32. A[M][K], Bw[N][K].
// ---------------------------------------------------------------------------
__global__ __launch_bounds__(256) void gemm_mfma_64_part(
    const unsigned short* __restrict__ A, const unsigned short* __restrict__ Bw,
    float* __restrict__ part, int K, int Ks) {
  __shared__ short As[64 * 64];
  __shared__ short Bs[64 * 64];
  int tid = threadIdx.x;
  int w = tid >> 6, lane = tid & 63;
  int quad = lane >> 4, l16 = lane & 15;
  int m0 = blockIdx.y * 64, n0 = blockIdx.x * 64;
  int bz = blockIdx.z;
  int wm = w >> 1, wn = w & 1;

  const char* pA = (const char*)A +
      ((size_t)(m0 + 16 * w + (lane >> 3)) * K + (size_t)bz * Ks) * 2 +
      (lane & 7) * 16;
  const char* pB = (const char*)Bw +
      ((size_t)(n0 + 16 * w + (lane >> 3)) * K + (size_t)bz * Ks) * 2 +
      (lane & 7) * 16;
  short* la = &As[w * 1024];
  short* lb = &Bs[w * 1024];
  const size_t rstep = (size_t)K * 2 * 8;  // +8 rows

  f32x4 acc[2][2] = {};
  int aoff[2], boff[2];
#pragma unroll
  for (int t = 0; t < 2; ++t) {
    aoff[t] = (wm * 32 + t * 16 + l16) * 64 + quad * 8;
    boff[t] = (wn * 32 + t * 16 + l16) * 64 + quad * 8;
  }

  for (int kk = 0; kk < K /*unused*/ && kk < Ks; kk += 64) {}
  for (int kk = 0; kk < Ks; kk += 64) {
    __syncthreads();
    gll16(pA, la);
    gll16(pA + rstep, la + 512);
    gll16(pB, lb);
    gll16(pB + rstep, lb + 512);
    pA += 128; pB += 128;
    __syncthreads();
#pragma unroll
    for (int ks = 0; ks < 2; ++ks) {
      bf16x8 af[2], bfr[2];
#pragma unroll
      for (int t = 0; t < 2; ++t) af[t] = *(const bf16x8*)&As[aoff[t] + ks * 32];
#pragma unroll
      for (int t = 0; t < 2; ++t) bfr[t] = *(const bf16x8*)&Bs[boff[t] + ks * 32];
#pragma unroll
      for (int mt = 0; mt < 2; ++mt)
#pragma unroll
        for (int nt = 0; nt < 2; ++nt)
          acc[mt][nt] = __builtin_amdgcn_mfma_f32_16x16x32_bf16(
              af[mt], bfr[nt], acc[mt][nt], 0, 0, 0);
    }
  }
  float* pp = part + (size_t)bz * (OUT1 * NROI);
#pragma unroll
  for (int mt = 0; mt < 2; ++mt)
#pragma unroll
    for (int nt = 0; nt < 2; ++nt) {
      int col = n0 + wn * 32 + nt * 16 + l16;
#pragma unroll
      for (int r = 0; r < 4; ++r) {
        int row = m0 + wm * 32 + mt * 16 + quad * 4 + r;
        pp[(size_t)row * OUT1 + col] = acc[mt][nt][r];
      }
    }
}

// ---------------------------------------------------------------------------
// Head: x2 = relu(sum_z part2[z] + b2); 16-way GEMV with packed bf16 Wcat
// (coalesced uint4 reads) + wave shuffle reduce; box decode.
// ---------------------------------------------------------------------------
__global__ __launch_bounds__(256) void head_kernel(
    const float* __restrict__ P, const float* __restrict__ b2,
    const unsigned short* __restrict__ Wcat, const float* __restrict__ bcat,
    const float* __restrict__ props, float* __restrict__ out) {
  __shared__ float xrow[1024];
  __shared__ float res[16];
  int row = blockIdx.x;
  int tid = threadIdx.x;
  int wave = tid >> 6, lane = tid & 63;
  {
    size_t off = (size_t)row * 1024 + tid * 4;
    float4 a = *(const float4*)(P + off);
#pragma unroll
    for (int z = 1; z < SK2; ++z) {
      float4 t = *(const float4*)(P + (size_t)z * (NROI * OUT1) + off);
      a.x += t.x; a.y += t.y; a.z += t.z; a.w += t.w;
    }
    float4 bv = *(const float4*)(b2 + tid * 4);
    xrow[tid * 4 + 0] = fmaxf(a.x + bv.x, 0.f);
    xrow[tid * 4 + 1] = fmaxf(a.y + bv.y, 0.f);
    xrow[tid * 4 + 2] = fmaxf(a.z + bv.z, 0.f);
    xrow[tid * 4 + 3] = fmaxf(a.w + bv.w, 0.f);
  }
  __syncthreads();
#pragma unroll
  for (int oo = 0; oo < 4; ++oo) {
    int o = wave * 4 + oo;
    const unsigned short* wr = Wcat + (size_t)o * OUT1;
    float s = 0.f;
#pragma unroll
    for (int pass = 0; pass < 2; ++pass) {
      int k = pass * 512 + lane * 8;
      uint4 v = *(const uint4*)(wr + k);
      float4 x0 = *(const float4*)&xrow[k];
      float4 x1 = *(const float4*)&xrow[k + 4];
      s += __uint_as_float(v.x << 16) * x0.x;
      s += __uint_as_float(v.x & 0xFFFF0000u) * x0.y;
      s += __uint_as_float(v.y << 16) * x0.z;
      s += __uint_as_float(v.y & 0xFFFF0000u) * x0.w;
      s += __uint_as_float(v.z << 16) * x1.x;
      s += __uint_as_float(v.z & 0xFFFF0000u) * x1.y;
      s += __uint_as_float(v.w << 16) * x1.z;
      s += __uint_as_float(v.w & 0xFFFF0000u) * x1.w;
    }
#pragma unroll
    for (int d = 32; d > 0; d >>= 1) s += __shfl_down(s, d);
    if (lane == 0) res[o] = s + bcat[o];
  }
  __syncthreads();
  if (tid < NCLS) out[5120 + (size_t)row * NCLS + tid] = res[tid];
  if (tid == 0) {
    const float* p = props + (size_t)row * 5;
    float p0 = p[0] * 4.f, p1 = p[1] * 4.f, p2 = p[2] * 4.f, p3 = p[3] * 4.f,
          p4 = p[4];
    float r0 = res[11], r1 = res[12], r2 = res[13], r3 = res[14], r4 = res[15];
    const float V = 4.135166556742356f;  // |log(16/1000)|
    float bx = p2 * r0 + p0;
    float by = p3 * r1 + p1;
    float bw = p2 * expf(fminf(fmaxf(r2, -V), V));
    float bh = p3 * expf(fminf(fmaxf(r3, -V), V));
    const float PI = 3.14159265358979323846f;
    float a = p4 + r4;
    float m = fmodf(a + PI * 0.5f, PI);
    if (m < 0.f) m += PI;
    float ba = m - PI * 0.5f;
    float* bo = out + (size_t)row * 5;
    bo[0] = bx; bo[1] = by; bo[2] = bw; bo[3] = bh; bo[4] = ba;
  }
}

// ---------------------------------------------------------------------------
extern "C" void kernel_launch(void* const* d_in, const int* in_sizes, int n_in,
                              void* d_out, int out_size, void* d_ws,
                              size_t ws_size, hipStream_t stream) {
  const float* feat  = (const float*)d_in[0];
  const float* props = (const float*)d_in[1];
  const float* W1    = (const float*)d_in[2];
  const float* b1    = (const float*)d_in[3];
  const float* W2    = (const float*)d_in[4];
  const float* b2    = (const float*)d_in[5];
  const float* Wcls  = (const float*)d_in[6];
  const float* bcls  = (const float*)d_in[7];
  const float* Wreg  = (const float*)d_in[8];
  const float* breg  = (const float*)d_in[9];
  float* out = (float*)d_out;

  char* wp = (char*)d_ws;
  unsigned short* pooled = (unsigned short*)wp; wp += (size_t)NROI * DIN * 2;
  unsigned short* W1T    = (unsigned short*)wp; wp += (size_t)OUT1 * DIN * 2;
  unsigned short* W2T    = (unsigned short*)wp; wp += (size_t)OUT1 * OUT1 * 2;
  unsigned short* x1     = (unsigned short*)wp; wp += (size_t)NROI * OUT1 * 2;
  unsigned short* part1  = (unsigned short*)wp; wp += (size_t)SK1 * NROI * OUT1 * 2;
  float*          part2  = (float*)wp;          wp += (size_t)SK2 * NROI * OUT1 * 4;
  unsigned short* Wcat   = (unsigned short*)wp; wp += (size_t)16 * OUT1 * 2;
  float*          bcat   = (float*)wp;          wp += 16 * 4;
  unsigned short* fhwc   = (unsigned short*)wp;

  size_t need_min  = (size_t)(wp - (char*)d_ws);
  size_t need_full = need_min + (size_t)BB * CC * HH * WW * 2;

  if (ws_size >= need_full) {
    transpose_to_hwc_bf16<<<dim3(HH * WW / 128, CC / 128, BB), 256, 0, stream>>>(
        feat, fhwc);
    roi_align_hwc<<<NROI, 256, 0, stream>>>(fhwc, props, pooled);
  } else {
    roi_align_nchw<<<NROI, 256, 0, stream>>>(feat, props, pooled);
  }

  cvt_w_t<<<dim3(DIN / 64, OUT1 / 256), 256, 0, stream>>>(W1, W1T, DIN);
  cvt_w_t<<<dim3(OUT1 / 64, OUT1 / 256), 256, 0, stream>>>(W2, W2T, OUT1);
  pack_head_w<<<16, 256, 0, stream>>>(Wcls, bcls, Wreg, breg, Wcat, bcat);

  gemm_mfma_128<<<dim3(8, 8, SK1), 256, 0, stream>>>(pooled, W1T, part1, DIN,
                                                     DIN / SK1);
  reduce_relu_bf16<<<NROI * OUT1 / 2048, 256, 0, stream>>>(part1, b1, x1);
  gemm_mfma_64_part<<<dim3(16, 16, SK2), 256, 0, stream>>>(x1, W2T, part2, OUT1,
                                                           OUT1 / SK2);
  head_kernel<<<NROI, 256, 0, stream>>>(part2, b2, Wcat, bcat, props, out);
}

// Round 7
// 394.754 us; speedup vs baseline: 1.0554x; 1.0554x over previous
//
#include <hip/hip_runtime.h>
#include <math.h>
#include <stdint.h>

#define BB 2
#define NN 512
#define CC 256
#define HH 256
#define WW 256
#define DIN 12544    // C * 7 * 7
#define OUT1 1024
#define NCLS 11      // NUM_CLASSES + 1
#define NROI 1024    // B * N
#define SK1 8        // split-K for FC1 (12544 = 8 * 1568)
#define SK2 2        // split-K for FC2 (1024 = 2 * 512)

typedef short bf16x8 __attribute__((ext_vector_type(8)));
typedef float f32x4 __attribute__((ext_vector_type(4)));

__device__ inline unsigned short f2bf(float f) {
  unsigned int u = __float_as_uint(f);
  u += 0x7FFF + ((u >> 16) & 1);  // round-to-nearest-even
  return (unsigned short)(u >> 16);
}
__device__ inline float bf2f(unsigned short h) {
  return __uint_as_float(((unsigned int)h) << 16);
}
__device__ inline float4 ld_bf4(const unsigned short* p) {
  ushort4 r = *(const ushort4*)p;
  return make_float4(bf2f(r.x), bf2f(r.y), bf2f(r.z), bf2f(r.w));
}

// async global->LDS, 16B per lane; lds ptr must be wave-uniform base + lane*16
__device__ inline void gll16(const void* g, void* l) {
  __builtin_amdgcn_global_load_lds(
      reinterpret_cast<const __attribute__((address_space(1))) void*>(
          reinterpret_cast<uintptr_t>(g)),
      reinterpret_cast<__attribute__((address_space(3))) void*>(
          (unsigned int)reinterpret_cast<uintptr_t>(l)),
      16, 0, 0);
}

// ---------------------------------------------------------------------------
// NCHW fp32 -> NHWC bf16, v2. Tile 128c x 128hw. All 16 loads register-staged,
// 512B read bursts, 256B contiguous write bursts. LDS bf16 [hw][c] stride 132.
// ---------------------------------------------------------------------------
__global__ __launch_bounds__(256) void transpose_to_hwc_bf16(
    const float* __restrict__ in, unsigned short* __restrict__ out) {
  __shared__ unsigned short tile[128 * 132];
  int b = blockIdx.z;
  int hw0 = blockIdx.x * 128;
  int c0 = blockIdx.y * 128;
  int tid = threadIdx.x;
  int hl = tid & 31;  // hw chunk lane
  int hr = tid >> 5;  // 0..7: c row group
  const float* base = in + ((size_t)b * CC + c0) * (HH * WW) + hw0;
  float4 v[16];
#pragma unroll
  for (int p = 0; p < 16; ++p) {
    int c = p * 8 + hr;
    v[p] = *(const float4*)(base + (size_t)c * (HH * WW) + hl * 4);
  }
#pragma unroll
  for (int p = 0; p < 16; ++p) {
    int c = p * 8 + hr;
    int hw = hl * 4;
    tile[(hw + 0) * 132 + c] = f2bf(v[p].x);
    tile[(hw + 1) * 132 + c] = f2bf(v[p].y);
    tile[(hw + 2) * 132 + c] = f2bf(v[p].z);
    tile[(hw + 3) * 132 + c] = f2bf(v[p].w);
  }
  __syncthreads();
  unsigned short* ob = out + ((size_t)b * (HH * WW) + hw0) * CC + c0;
#pragma unroll
  for (int p = 0; p < 16; ++p) {
    int r = p * 8 + hr;
    ushort4 o = *(const ushort4*)&tile[r * 132 + hl * 4];
    *(ushort4*)(ob + (size_t)r * CC + hl * 4) = o;
  }
}

// ---------------------------------------------------------------------------
__device__ inline void bilin(float gy, float gx, int& y0, int& x0, int& y1,
                             int& x1, float& w00, float& w01, float& w10,
                             float& w11) {
  float valid = (gy > -1.f && gy < 256.f && gx > -1.f && gx < 256.f) ? 0.25f : 0.f;
  float y = fminf(fmaxf(gy, 0.f), 255.f);
  float x = fminf(fmaxf(gx, 0.f), 255.f);
  float yf = floorf(y), xf = floorf(x);
  y0 = (int)yf; x0 = (int)xf;
  y1 = min(y0 + 1, 255); x1 = min(x0 + 1, 255);
  float ly = y - yf, lx = x - xf, hy = 1.f - ly, hx = 1.f - lx;
  w00 = hy * hx * valid; w01 = hy * lx * valid;
  w10 = ly * hx * valid; w11 = ly * lx * valid;
}

// ---------------------------------------------------------------------------
// ROI align rotated from NHWC bf16. pooled (bf16) [roi][bin*256 + c] (bin-
// major). Grid (NROI, 2): 8 global waves per ROI stride the 49 bins; direct
// coalesced ushort4 stores, no LDS, no barrier -> 2x resident waves vs r6.
// ---------------------------------------------------------------------------
__global__ __launch_bounds__(256) void roi_align_hwc(
    const unsigned short* __restrict__ fhwc, const float* __restrict__ props,
    unsigned short* __restrict__ pooled) {
  int roi = blockIdx.x;
  int b = roi >> 9;
  const float* p = props + (size_t)roi * 5;
  float cx = p[0], cy = p[1], w = p[2], h = p[3], th = p[4];
  float sn = sinf(th), cs = cosf(th);
  int gw = blockIdx.y * 4 + (threadIdx.x >> 6);  // 0..7 global wave id
  int lane = threadIdx.x & 63;
  int c4 = lane * 4;
  const unsigned short* fb = fhwc + (size_t)b * HH * WW * CC;
  unsigned short* outp = pooled + (size_t)roi * DIN;

  for (int bin = gw; bin < 49; bin += 8) {
    int py = bin / 7, px = bin - py * 7;
    float a0 = 0.f, a1 = 0.f, a2 = 0.f, a3 = 0.f;
#pragma unroll
    for (int sy = 0; sy < 2; ++sy) {
#pragma unroll
      for (int sx = 0; sx < 2; ++sx) {
        float ys = -0.5f * h + (h / 7.0f) * ((float)py + ((float)sy + 0.5f) * 0.5f);
        float xs = -0.5f * w + (w / 7.0f) * ((float)px + ((float)sx + 0.5f) * 0.5f);
        float gx = cx + xs * cs - ys * sn;
        float gy = cy + xs * sn + ys * cs;
        int y0, x0, y1, x1; float w00, w01, w10, w11;
        bilin(gy, gx, y0, x0, y1, x1, w00, w01, w10, w11);
        float4 v00 = ld_bf4(fb + ((size_t)(y0 * WW + x0)) * CC + c4);
        float4 v01 = ld_bf4(fb + ((size_t)(y0 * WW + x1)) * CC + c4);
        float4 v10 = ld_bf4(fb + ((size_t)(y1 * WW + x0)) * CC + c4);
        float4 v11 = ld_bf4(fb + ((size_t)(y1 * WW + x1)) * CC + c4);
        a0 += w00 * v00.x + w01 * v01.x + w10 * v10.x + w11 * v11.x;
        a1 += w00 * v00.y + w01 * v01.y + w10 * v10.y + w11 * v11.y;
        a2 += w00 * v00.z + w01 * v01.z + w10 * v10.z + w11 * v11.z;
        a3 += w00 * v00.w + w01 * v01.w + w10 * v10.w + w11 * v11.w;
      }
    }
    ushort4 o;
    o.x = f2bf(a0); o.y = f2bf(a1); o.z = f2bf(a2); o.w = f2bf(a3);
    *(ushort4*)(outp + bin * 256 + c4) = o;
  }
}

// Fallback: direct NCHW gather (small-ws path), bin-major layout
__global__ __launch_bounds__(256) void roi_align_nchw(
    const float* __restrict__ feat, const float* __restrict__ props,
    unsigned short* __restrict__ pooled) {
  int roi = blockIdx.x;
  int b = roi >> 9;
  int c = threadIdx.x;
  const float* p = props + (size_t)roi * 5;
  float cx = p[0], cy = p[1], w = p[2], h = p[3], th = p[4];
  float sn = sinf(th), cs = cosf(th);
  const float* fb = feat + ((size_t)b * CC + c) * (HH * WW);
  unsigned short* outp = pooled + (size_t)roi * DIN;
  for (int bin = 0; bin < 49; ++bin) {
    int py = bin / 7, px = bin - py * 7;
    float acc = 0.f;
#pragma unroll
    for (int sy = 0; sy < 2; ++sy) {
#pragma unroll
      for (int sx = 0; sx < 2; ++sx) {
        float ys = -0.5f * h + (h / 7.0f) * ((float)py + ((float)sy + 0.5f) * 0.5f);
        float xs = -0.5f * w + (w / 7.0f) * ((float)px + ((float)sx + 0.5f) * 0.5f);
        float gx = cx + xs * cs - ys * sn;
        float gy = cy + xs * sn + ys * cs;
        int y0, x0, y1, x1; float w00, w01, w10, w11;
        bilin(gy, gx, y0, x0, y1, x1, w00, w01, w10, w11);
        acc += w00 * fb[(size_t)y0 * WW + x0] + w01 * fb[(size_t)y0 * WW + x1] +
               w10 * fb[(size_t)y1 * WW + x0] + w11 * fb[(size_t)y1 * WW + x1];
      }
    }
    outp[bin * 256 + c] = f2bf(acc);
  }
}

// ---------------------------------------------------------------------------
// Weight convert (round-3 proven): out[n][k'] = bf16(in[perm(k')][n]);
// perm(k') = (k'&255)*49 + (k'>>8) when PERM. Tile 64x64 via LDS.
// ---------------------------------------------------------------------------
template <bool PERM>
__global__ __launch_bounds__(256) void cvt_w(const float* __restrict__ in,
                                             unsigned short* __restrict__ out,
                                             int N, int Kout) {
  __shared__ float tile[64][65];
  int k0 = blockIdx.x * 64, n0 = blockIdx.y * 64;
  int tid = threadIdx.x;
  int hi = tid >> 4, lo = tid & 15;
#pragma unroll
  for (int pass = 0; pass < 4; ++pass) {
    int ki = hi + pass * 16;
    int k = k0 + ki;
    int row = PERM ? ((k & 255) * 49 + (k >> 8)) : k;
    float4 v = *(const float4*)(in + (size_t)row * N + n0 + lo * 4);
    tile[ki][lo * 4 + 0] = v.x;
    tile[ki][lo * 4 + 1] = v.y;
    tile[ki][lo * 4 + 2] = v.z;
    tile[ki][lo * 4 + 3] = v.w;
  }
  __syncthreads();
#pragma unroll
  for (int pass = 0; pass < 4; ++pass) {
    int nl = hi + pass * 16;
    int kq = lo * 4;
    ushort4 o;
    o.x = f2bf(tile[kq + 0][nl]);
    o.y = f2bf(tile[kq + 1][nl]);
    o.z = f2bf(tile[kq + 2][nl]);
    o.w = f2bf(tile[kq + 3][nl]);
    *(ushort4*)(out + (size_t)(n0 + nl) * Kout + k0 + kq) = o;
  }
}

// ---------------------------------------------------------------------------
// Pack head weights: Wcat bf16 [16][1024]; bcat[16].
// ---------------------------------------------------------------------------
__global__ __launch_bounds__(256) void pack_head_w(
    const float* __restrict__ Wcls, const float* __restrict__ bcls,
    const float* __restrict__ Wreg, const float* __restrict__ breg,
    unsigned short* __restrict__ Wcat, float* __restrict__ bcat) {
  int o = blockIdx.x;
  int t = threadIdx.x;
#pragma unroll
  for (int j = 0; j < 4; ++j) {
    int k = t * 4 + j;
    float v = (o < NCLS) ? Wcls[(size_t)k * NCLS + o]
                         : Wreg[(size_t)k * 5 + (o - NCLS)];
    Wcat[(size_t)o * OUT1 + k] = f2bf(v);
  }
  if (t == 0) bcat[o] = (o < NCLS) ? bcls[o] : breg[o - NCLS];
}

// ---------------------------------------------------------------------------
// MFMA GEMM, 128x128 tile, BK=32, split-K partials -> bf16.
// A [M][K] bf16 row-major; Bw [N][K] bf16 row-major.
// ---------------------------------------------------------------------------
__global__ __launch_bounds__(256) void gemm_mfma_128(
    const unsigned short* __restrict__ A, const unsigned short* __restrict__ Bw,
    unsigned short* __restrict__ part, int K, int Ks) {
  __shared__ short As[128 * 32];
  __shared__ short Bs[128 * 32];
  int tid = threadIdx.x;
  int w = tid >> 6, lane = tid & 63;
  int quad = lane >> 4, l16 = lane & 15;
  int m0 = blockIdx.y * 128, n0 = blockIdx.x * 128;
  int bz = blockIdx.z;
  int wm = w >> 1, wn = w & 1;

  const char* pA = (const char*)A +
      ((size_t)(m0 + 32 * w + (lane >> 2)) * K + (size_t)bz * Ks) * 2 +
      (lane & 3) * 16;
  const char* pB = (const char*)Bw +
      ((size_t)(n0 + 32 * w + (lane >> 2)) * K + (size_t)bz * Ks) * 2 +
      (lane & 3) * 16;
  short* la = &As[w * 1024];
  short* lb = &Bs[w * 1024];
  const size_t rstep = (size_t)K * 2 * 16;  // +16 rows

  f32x4 acc[4][4] = {};
  int aoff[4], boff[4];
#pragma unroll
  for (int t = 0; t < 4; ++t) {
    aoff[t] = (wm * 64 + t * 16 + l16) * 32 + quad * 8;
    boff[t] = (wn * 64 + t * 16 + l16) * 32 + quad * 8;
  }

  for (int kk = 0; kk < Ks; kk += 32) {
    __syncthreads();  // prior reads done before LDS overwrite
    gll16(pA, la);
    gll16(pA + rstep, la + 512);
    gll16(pB, lb);
    gll16(pB + rstep, lb + 512);
    pA += 64; pB += 64;
    __syncthreads();  // vmcnt(0) drained -> LDS valid
    bf16x8 af[4], bfr[4];
#pragma unroll
    for (int t = 0; t < 4; ++t) af[t] = *(const bf16x8*)&As[aoff[t]];
#pragma unroll
    for (int t = 0; t < 4; ++t) bfr[t] = *(const bf16x8*)&Bs[boff[t]];
#pragma unroll
    for (int mt = 0; mt < 4; ++mt)
#pragma unroll
      for (int nt = 0; nt < 4; ++nt)
        acc[mt][nt] = __builtin_amdgcn_mfma_f32_16x16x32_bf16(
            af[mt], bfr[nt], acc[mt][nt], 0, 0, 0);
  }

  unsigned short* pp = part + (size_t)bz * (OUT1 * NROI);
#pragma unroll
  for (int mt = 0; mt < 4; ++mt)
#pragma unroll
    for (int nt = 0; nt < 4; ++nt) {
      int col = n0 + wn * 64 + nt * 16 + l16;
#pragma unroll
      for (int r = 0; r < 4; ++r) {
        int row = m0 + wm * 64 + mt * 16 + quad * 4 + r;
        pp[(size_t)row * OUT1 + col] = f2bf(acc[mt][nt][r]);
      }
    }
}

// split-K reduce + bias + relu -> bf16 (SK1 bf16 partials), 8 elems/thread
__global__ __launch_bounds__(256) void reduce_relu_bf16(
    const unsigned short* __restrict__ part, const float* __restrict__ bias,
    unsigned short* __restrict__ out) {
  int i = blockIdx.x * 256 + threadIdx.x;  // ushort8 index
  int base = i * 8;
  int col = base & (OUT1 - 1);
  float s[8] = {};
#pragma unroll
  for (int z = 0; z < SK1; ++z) {
    uint4 v = *(const uint4*)(part + (size_t)z * (NROI * OUT1) + base);
    s[0] += __uint_as_float(v.x << 16);
    s[1] += __uint_as_float(v.x & 0xFFFF0000u);
    s[2] += __uint_as_float(v.y << 16);
    s[3] += __uint_as_float(v.y & 0xFFFF0000u);
    s[4] += __uint_as_float(v.z << 16);
    s[5] += __uint_as_float(v.z & 0xFFFF0000u);
    s[6] += __uint_as_float(v.w << 16);
    s[7] += __uint_as_float(v.w & 0xFFFF0000u);
  }
  float4 b0 = *(const float4*)(bias + col);
  float4 b1 = *(const float4*)(bias + col + 4);
  uint4 o;
  o.x = (unsigned int)f2bf(fmaxf(s[0] + b0.x, 0.f)) |
        ((unsigned int)f2bf(fmaxf(s[1] + b0.y, 0.f)) << 16);
  o.y = (unsigned int)f2bf(fmaxf(s[2] + b0.z, 0.f)) |
        ((unsigned int)f2bf(fmaxf(s[3] + b0.w, 0.f)) << 16);
  o.z = (unsigned int)f2bf(fmaxf(s[4] + b1.x, 0.f)) |
        ((unsigned int)f2bf(fmaxf(s[5] + b1.y, 0.f)) << 16);
  o.w = (unsigned int)f2bf(fmaxf(s[6] + b1.z, 0.f)) |
        ((unsigned int)f2bf(fmaxf(s[7] + b1.w, 0.f)) << 16);
  *(uint4*)(out + base) = o;
}

// ---------------------------------------------------------------------------
// MFMA GEMM, 64x64 tile, BK=64, split-K partials fp32. A[M][K], Bw[N][K].
// ---------------------------------------------------------------------------
__global__ __launch_bounds__(256) void gemm_mfma_64_part(
    const unsigned short* __restrict__ A, const unsigned short* __restrict__ Bw,
    float* __restrict__ part, int K, int Ks) {
  __shared__ short As[64 * 64];
  __shared__ short Bs[64 * 64];
  int tid = threadIdx.x;
  int w = tid >> 6, lane = tid & 63;
  int quad = lane >> 4, l16 = lane & 15;
  int m0 = blockIdx.y * 64, n0 = blockIdx.x * 64;
  int bz = blockIdx.z;
  int wm = w >> 1, wn = w & 1;

  const char* pA = (const char*)A +
      ((size_t)(m0 + 16 * w + (lane >> 3)) * K + (size_t)bz * Ks) * 2 +
      (lane & 7) * 16;
  const char* pB = (const char*)Bw +
      ((size_t)(n0 + 16 * w + (lane >> 3)) * K + (size_t)bz * Ks) * 2 +
      (lane & 7) * 16;
  short* la = &As[w * 1024];
  short* lb = &Bs[w * 1024];
  const size_t rstep = (size_t)K * 2 * 8;  // +8 rows

  f32x4 acc[2][2] = {};
  int aoff[2], boff[2];
#pragma unroll
  for (int t = 0; t < 2; ++t) {
    aoff[t] = (wm * 32 + t * 16 + l16) * 64 + quad * 8;
    boff[t] = (wn * 32 + t * 16 + l16) * 64 + quad * 8;
  }

  for (int kk = 0; kk < Ks; kk += 64) {
    __syncthreads();
    gll16(pA, la);
    gll16(pA + rstep, la + 512);
    gll16(pB, lb);
    gll16(pB + rstep, lb + 512);
    pA += 128; pB += 128;
    __syncthreads();
#pragma unroll
    for (int ks = 0; ks < 2; ++ks) {
      bf16x8 af[2], bfr[2];
#pragma unroll
      for (int t = 0; t < 2; ++t) af[t] = *(const bf16x8*)&As[aoff[t] + ks * 32];
#pragma unroll
      for (int t = 0; t < 2; ++t) bfr[t] = *(const bf16x8*)&Bs[boff[t] + ks * 32];
#pragma unroll
      for (int mt = 0; mt < 2; ++mt)
#pragma unroll
        for (int nt = 0; nt < 2; ++nt)
          acc[mt][nt] = __builtin_amdgcn_mfma_f32_16x16x32_bf16(
              af[mt], bfr[nt], acc[mt][nt], 0, 0, 0);
    }
  }
  float* pp = part + (size_t)bz * (OUT1 * NROI);
#pragma unroll
  for (int mt = 0; mt < 2; ++mt)
#pragma unroll
    for (int nt = 0; nt < 2; ++nt) {
      int col = n0 + wn * 32 + nt * 16 + l16;
#pragma unroll
      for (int r = 0; r < 4; ++r) {
        int row = m0 + wm * 32 + mt * 16 + quad * 4 + r;
        pp[(size_t)row * OUT1 + col] = acc[mt][nt][r];
      }
    }
}

// ---------------------------------------------------------------------------
// Head: x2 = relu(sum_z part2[z] + b2); 16-way GEMV with packed bf16 Wcat
// + wave shuffle reduce; box decode.
// ---------------------------------------------------------------------------
__global__ __launch_bounds__(256) void head_kernel(
    const float* __restrict__ P, const float* __restrict__ b2,
    const unsigned short* __restrict__ Wcat, const float* __restrict__ bcat,
    const float* __restrict__ props, float* __restrict__ out) {
  __shared__ float xrow[1024];
  __shared__ float res[16];
  int row = blockIdx.x;
  int tid = threadIdx.x;
  int wave = tid >> 6, lane = tid & 63;
  {
    size_t off = (size_t)row * 1024 + tid * 4;
    float4 a = *(const float4*)(P + off);
#pragma unroll
    for (int z = 1; z < SK2; ++z) {
      float4 t = *(const float4*)(P + (size_t)z * (NROI * OUT1) + off);
      a.x += t.x; a.y += t.y; a.z += t.z; a.w += t.w;
    }
    float4 bv = *(const float4*)(b2 + tid * 4);
    xrow[tid * 4 + 0] = fmaxf(a.x + bv.x, 0.f);
    xrow[tid * 4 + 1] = fmaxf(a.y + bv.y, 0.f);
    xrow[tid * 4 + 2] = fmaxf(a.z + bv.z, 0.f);
    xrow[tid * 4 + 3] = fmaxf(a.w + bv.w, 0.f);
  }
  __syncthreads();
#pragma unroll
  for (int oo = 0; oo < 4; ++oo) {
    int o = wave * 4 + oo;
    const unsigned short* wr = Wcat + (size_t)o * OUT1;
    float s = 0.f;
#pragma unroll
    for (int pass = 0; pass < 2; ++pass) {
      int k = pass * 512 + lane * 8;
      uint4 v = *(const uint4*)(wr + k);
      float4 x0 = *(const float4*)&xrow[k];
      float4 x1 = *(const float4*)&xrow[k + 4];
      s += __uint_as_float(v.x << 16) * x0.x;
      s += __uint_as_float(v.x & 0xFFFF0000u) * x0.y;
      s += __uint_as_float(v.y << 16) * x0.z;
      s += __uint_as_float(v.y & 0xFFFF0000u) * x0.w;
      s += __uint_as_float(v.z << 16) * x1.x;
      s += __uint_as_float(v.z & 0xFFFF0000u) * x1.y;
      s += __uint_as_float(v.w << 16) * x1.z;
      s += __uint_as_float(v.w & 0xFFFF0000u) * x1.w;
    }
#pragma unroll
    for (int d = 32; d > 0; d >>= 1) s += __shfl_down(s, d);
    if (lane == 0) res[o] = s + bcat[o];
  }
  __syncthreads();
  if (tid < NCLS) out[5120 + (size_t)row * NCLS + tid] = res[tid];
  if (tid == 0) {
    const float* p = props + (size_t)row * 5;
    float p0 = p[0] * 4.f, p1 = p[1] * 4.f, p2 = p[2] * 4.f, p3 = p[3] * 4.f,
          p4 = p[4];
    float r0 = res[11], r1 = res[12], r2 = res[13], r3 = res[14], r4 = res[15];
    const float V = 4.135166556742356f;  // |log(16/1000)|
    float bx = p2 * r0 + p0;
    float by = p3 * r1 + p1;
    float bw = p2 * expf(fminf(fmaxf(r2, -V), V));
    float bh = p3 * expf(fminf(fmaxf(r3, -V), V));
    const float PI = 3.14159265358979323846f;
    float a = p4 + r4;
    float m = fmodf(a + PI * 0.5f, PI);
    if (m < 0.f) m += PI;
    float ba = m - PI * 0.5f;
    float* bo = out + (size_t)row * 5;
    bo[0] = bx; bo[1] = by; bo[2] = bw; bo[3] = bh; bo[4] = ba;
  }
}

// ---------------------------------------------------------------------------
extern "C" void kernel_launch(void* const* d_in, const int* in_sizes, int n_in,
                              void* d_out, int out_size, void* d_ws,
                              size_t ws_size, hipStream_t stream) {
  const float* feat  = (const float*)d_in[0];
  const float* props = (const float*)d_in[1];
  const float* W1    = (const float*)d_in[2];
  const float* b1    = (const float*)d_in[3];
  const float* W2    = (const float*)d_in[4];
  const float* b2    = (const float*)d_in[5];
  const float* Wcls  = (const float*)d_in[6];
  const float* bcls  = (const float*)d_in[7];
  const float* Wreg  = (const float*)d_in[8];
  const float* breg  = (const float*)d_in[9];
  float* out = (float*)d_out;

  char* wp = (char*)d_ws;
  unsigned short* pooled = (unsigned short*)wp; wp += (size_t)NROI * DIN * 2;
  unsigned short* W1T    = (unsigned short*)wp; wp += (size_t)OUT1 * DIN * 2;
  unsigned short* W2T    = (unsigned short*)wp; wp += (size_t)OUT1 * OUT1 * 2;
  unsigned short* x1     = (unsigned short*)wp; wp += (size_t)NROI * OUT1 * 2;
  unsigned short* part1  = (unsigned short*)wp; wp += (size_t)SK1 * NROI * OUT1 * 2;
  float*          part2  = (float*)wp;          wp += (size_t)SK2 * NROI * OUT1 * 4;
  unsigned short* Wcat   = (unsigned short*)wp; wp += (size_t)16 * OUT1 * 2;
  float*          bcat   = (float*)wp;          wp += 16 * 4;
  unsigned short* fhwc   = (unsigned short*)wp;

  size_t need_min  = (size_t)(wp - (char*)d_ws);
  size_t need_full = need_min + (size_t)BB * CC * HH * WW * 2;

  if (ws_size >= need_full) {
    transpose_to_hwc_bf16<<<dim3(HH * WW / 128, CC / 128, BB), 256, 0, stream>>>(
        feat, fhwc);
    roi_align_hwc<<<dim3(NROI, 2), 256, 0, stream>>>(fhwc, props, pooled);
  } else {
    roi_align_nchw<<<NROI, 256, 0, stream>>>(feat, props, pooled);
  }

  cvt_w<true><<<dim3(DIN / 64, OUT1 / 64), 256, 0, stream>>>(W1, W1T, OUT1, DIN);
  cvt_w<false><<<dim3(OUT1 / 64, OUT1 / 64), 256, 0, stream>>>(W2, W2T, OUT1,
                                                               OUT1);
  pack_head_w<<<16, 256, 0, stream>>>(Wcls, bcls, Wreg, breg, Wcat, bcat);

  gemm_mfma_128<<<dim3(8, 8, SK1), 256, 0, stream>>>(pooled, W1T, part1, DIN,
                                                     DIN / SK1);
  reduce_relu_bf16<<<NROI * OUT1 / 2048, 256, 0, stream>>>(part1, b1, x1);
  gemm_mfma_64_part<<<dim3(16, 16, SK2), 256, 0, stream>>>(x1, W2T, part2, OUT1,
                                                           OUT1 / SK2);
  head_kernel<<<NROI, 256, 0, stream>>>(part2, b2, Wcat, bcat, props, out);
}